// Round 1
// baseline (179.775 us; speedup 1.0000x reference)
//
#include <hip/hip_runtime.h>

#define BATCH   16384
#define NUM_NEG 64
#define NSAMP   65          // 1 target + 64 negatives
#define EMBED   128

// One block (256 threads = 4 waves) per batch row.
// Stage embed row + sample indices in LDS; each wave computes every-4th
// sample's dot-product with a fully-coalesced float2 row load + butterfly
// reduce; wave 0 finishes with an in-register 65-wide softmax.
__global__ __launch_bounds__(256)
void skipgram_kernel(const int* __restrict__ target,
                     const int* __restrict__ context,
                     const int* __restrict__ negatives,
                     const float* __restrict__ emb_table,
                     const float* __restrict__ w_table,
                     const float* __restrict__ b_table,
                     float* __restrict__ out)
{
    const int b    = blockIdx.x;
    const int tid  = threadIdx.x;
    const int wave = tid >> 6;
    const int lane = tid & 63;

    __shared__ float s_emb[EMBED];
    __shared__ int   s_idx[NSAMP];
    __shared__ float s_logit[NSAMP];

    // Stage context embedding row (coalesced 512B) and the 65 sample indices.
    if (tid < EMBED) {
        const int c = context[b];
        s_emb[tid] = emb_table[(size_t)c * EMBED + tid];
    }
    if (tid < NSAMP) {
        s_idx[tid] = (tid == 0) ? target[b] : negatives[b * NUM_NEG + (tid - 1)];
    }
    __syncthreads();

    // Each lane owns 2 consecutive embed elements (2-way LDS bank alias = free).
    const float ex = s_emb[2 * lane];
    const float ey = s_emb[2 * lane + 1];

    // Each wave handles samples  wave, wave+4, wave+8, ...
    for (int s = wave; s < NSAMP; s += 4) {
        const int idx = s_idx[s];
        const float2 w2 = *reinterpret_cast<const float2*>(
            &w_table[(size_t)idx * EMBED + 2 * lane]);
        float p = ex * w2.x + ey * w2.y;
        #pragma unroll
        for (int off = 32; off; off >>= 1)
            p += __shfl_xor(p, off, 64);
        if (lane == 0)
            s_logit[s] = p + b_table[idx];
    }
    __syncthreads();

    // Wave 0: softmax over 65 logits. Lane l owns logit l; lane 0 also owns 64.
    if (wave == 0) {
        const float x  = s_logit[lane];
        const float x2 = (lane == 0) ? s_logit[64] : -INFINITY;

        float m = fmaxf(x, x2);
        #pragma unroll
        for (int off = 32; off; off >>= 1)
            m = fmaxf(m, __shfl_xor(m, off, 64));

        const float p  = expf(x - m);
        const float p2 = (lane == 0) ? expf(x2 - m) : 0.0f;

        float sum = p + p2;
        #pragma unroll
        for (int off = 32; off; off >>= 1)
            sum += __shfl_xor(sum, off, 64);

        const float inv = 1.0f / sum;
        out[(size_t)b * NSAMP + lane] = p * inv;
        if (lane == 0)
            out[(size_t)b * NSAMP + 64] = p2 * inv;
    }
}

extern "C" void kernel_launch(void* const* d_in, const int* in_sizes, int n_in,
                              void* d_out, int out_size, void* d_ws, size_t ws_size,
                              hipStream_t stream)
{
    const int*   target    = (const int*)  d_in[0];
    const int*   context   = (const int*)  d_in[1];
    const int*   negatives = (const int*)  d_in[2];
    const float* emb_table = (const float*)d_in[3];
    const float* w_table   = (const float*)d_in[4];
    const float* b_table   = (const float*)d_in[5];
    float*       out       = (float*)      d_out;

    skipgram_kernel<<<BATCH, 256, 0, stream>>>(
        target, context, negatives, emb_table, w_table, b_table, out);
}

// Round 2
// 98.600 us; speedup vs baseline: 1.8233x; 1.8233x over previous
//
#include <hip/hip_runtime.h>

#define BATCH   16384
#define NUM_NEG 64
#define NSAMP   65          // 1 target + 64 negatives
#define EMBED   128

// One block (256 threads = 4 waves) per batch row.
// float4 row loads: 32 lanes cover one 512B w-row, so each wave fetches TWO
// samples per VMEM instruction. All 8 row loads + bias loads of a wave are
// batch-issued before any reduction to keep ~4KB/wave in flight.
__global__ __launch_bounds__(256)
void skipgram_kernel(const int* __restrict__ target,
                     const int* __restrict__ context,
                     const int* __restrict__ negatives,
                     const float* __restrict__ emb_table,
                     const float* __restrict__ w_table,
                     const float* __restrict__ b_table,
                     float* __restrict__ out)
{
    const int b    = blockIdx.x;
    const int tid  = threadIdx.x;
    const int wave = tid >> 6;          // 0..3
    const int half = (tid >> 5) & 1;    // 0: lanes 0-31, 1: lanes 32-63
    const int l32  = tid & 31;
    const int lane = tid & 63;

    __shared__ int   s_idx[NSAMP];
    __shared__ float s_logit[NSAMP];

    // Stage the 65 sample indices (coalesced-ish; negatives row is 256B).
    if (tid < NSAMP)
        s_idx[tid] = (tid == 0) ? target[b] : negatives[b * NUM_NEG + (tid - 1)];
    __syncthreads();

    // Context-embedding fragment: 4 consecutive elements per lane-of-32.
    // Same address across all halves/waves -> L1 broadcast after first fetch.
    const int c = context[b];
    const float4 e4 = *reinterpret_cast<const float4*>(
        &emb_table[(size_t)c * EMBED + 4 * l32]);

    // Samples 0..63: wave w, half h, iteration i -> s = 8*i + 2*w + h.
    // Batch-issue all 8 row loads + 8 bias loads first (max loads in flight).
    float4 w4[8];
    float  bias[8];
    #pragma unroll
    for (int i = 0; i < 8; ++i) {
        const int s   = 8 * i + 2 * wave + half;
        const int idx = s_idx[s];
        w4[i]   = *reinterpret_cast<const float4*>(
                      &w_table[(size_t)idx * EMBED + 4 * l32]);
        bias[i] = b_table[idx];
    }

    // Reduce: dot(e4, w4) summed across the 32-lane half; lane 0 of the half
    // holds the logit.
    #pragma unroll
    for (int i = 0; i < 8; ++i) {
        const int s = 8 * i + 2 * wave + half;
        float p = e4.x * w4[i].x + e4.y * w4[i].y
                + e4.z * w4[i].z + e4.w * w4[i].w;
        #pragma unroll
        for (int off = 16; off; off >>= 1)
            p += __shfl_xor(p, off, 32);
        if (l32 == 0)
            s_logit[s] = p + bias[i];
    }

    // Sample 64: wave 1, lanes 0-31 (keeps wave 0 free for the softmax tail).
    if (wave == 1 && half == 0) {
        const int idx = s_idx[64];
        const float4 v = *reinterpret_cast<const float4*>(
            &w_table[(size_t)idx * EMBED + 4 * l32]);
        const float bb = b_table[idx];
        float p = e4.x * v.x + e4.y * v.y + e4.z * v.z + e4.w * v.w;
        #pragma unroll
        for (int off = 16; off; off >>= 1)
            p += __shfl_xor(p, off, 32);
        if (l32 == 0)
            s_logit[64] = p + bb;
    }
    __syncthreads();

    // Wave 0: softmax over 65 logits. Lane l owns logit l; lane 0 also owns 64.
    if (wave == 0) {
        const float x  = s_logit[lane];
        const float x2 = (lane == 0) ? s_logit[64] : -INFINITY;

        float m = fmaxf(x, x2);
        #pragma unroll
        for (int off = 32; off; off >>= 1)
            m = fmaxf(m, __shfl_xor(m, off, 64));

        const float p  = __expf(x - m);
        const float p2 = (lane == 0) ? __expf(x2 - m) : 0.0f;

        float sum = p + p2;
        #pragma unroll
        for (int off = 32; off; off >>= 1)
            sum += __shfl_xor(sum, off, 64);

        const float inv = 1.0f / sum;
        out[(size_t)b * NSAMP + lane] = p * inv;
        if (lane == 0)
            out[(size_t)b * NSAMP + 64] = p2 * inv;
    }
}

extern "C" void kernel_launch(void* const* d_in, const int* in_sizes, int n_in,
                              void* d_out, int out_size, void* d_ws, size_t ws_size,
                              hipStream_t stream)
{
    const int*   target    = (const int*)  d_in[0];
    const int*   context   = (const int*)  d_in[1];
    const int*   negatives = (const int*)  d_in[2];
    const float* emb_table = (const float*)d_in[3];
    const float* w_table   = (const float*)d_in[4];
    const float* b_table   = (const float*)d_in[5];
    float*       out       = (float*)      d_out;

    skipgram_kernel<<<BATCH, 256, 0, stream>>>(
        target, context, negatives, emb_table, w_table, b_table, out);
}